// Round 13
// baseline (333.379 us; speedup 1.0000x reference)
//
#include <hip/hip_runtime.h>
#include <math.h>

#define D 128
#define LLEN 200
#define SLEN 50
#define CH 50     // stage-1 chunk rows; 4*50 = 200 exactly -> no tail path
#define TROWS 51  // tile rows (stage 2 needs [u_long]+50)
// f32 tile: 51 rows x 128 floats. XOR swizzle: phys col4 = logical col4 ^
// (row&7), applied at ds_write and at both read paths (involution).

typedef __attribute__((ext_vector_type(8))) short short8;
typedef __attribute__((ext_vector_type(4))) float f32x4;

// f32 -> bf16 round-to-nearest-even
__device__ __forceinline__ unsigned short f2bf(float f) {
  unsigned int u = __float_as_uint(f);
  return (unsigned short)((u + 0x7FFFu + ((u >> 16) & 1u)) >> 16);
}

__device__ __forceinline__ float wave_red_sum(float v) {
#pragma unroll
  for (int m = 32; m >= 1; m >>= 1) v += __shfl_xor(v, m, 64);
  return v;
}
// 256-thread block sum; ALL threads must call.
__device__ __forceinline__ float block_sum(float v, float* red) {
  v = wave_red_sum(v);
  if ((threadIdx.x & 63) == 0) red[threadIdx.x >> 6] = v;
  __syncthreads();
  v = red[0] + red[1] + red[2] + red[3];
  __syncthreads();
  return v;
}

// Gather one float4 slot into a named register (slot clamped to 1599 so the
// load is unconditional -> no predicated live-range merge / spill hazard).
// Source col is LINEAR; the XOR swizzle is applied at the ds_write instead.
#define GATHER(P, ROWARR, RBASE, IT)                   \
  do {                                                 \
    int s_ = tid + (IT) * 256;                         \
    if (s_ > 1599) s_ = 1599;                          \
    int gid_ = (ROWARR)[(RBASE) + (s_ >> 5)];          \
    if (gid_ < 0) gid_ = 0;                            \
    P = it4[(size_t)gid_ * 32 + (s_ & 31)];            \
  } while (0)

#define GATHER7(ROWARR, RBASE)                                     \
  do {                                                             \
    GATHER(P0, ROWARR, RBASE, 0); GATHER(P1, ROWARR, RBASE, 1);    \
    GATHER(P2, ROWARR, RBASE, 2); GATHER(P3, ROWARR, RBASE, 3);    \
    GATHER(P4, ROWARR, RBASE, 4); GATHER(P5, ROWARR, RBASE, 5);    \
    GATHER(P6, ROWARR, RBASE, 6);                                  \
  } while (0)

// Write slot s to tile row (s>>5)+ROFF at phys col (s&31)^(row&7): one
// ds_write_b128. IT=6 threads with s>=1600 skip (their P is a clamped dup).
#define WSLOT(P, IT, ROFF)                                                  \
  do {                                                                      \
    int s_ = tid + (IT) * 256;                                              \
    if (s_ < 1600) {                                                        \
      int r_ = (s_ >> 5) + (ROFF);                                          \
      reinterpret_cast<float4*>(&ebuf[r_ * 128])[(s_ & 31) ^ (r_ & 7)] = P; \
    }                                                                       \
  } while (0)

#define WRITE7(ROFF)                                            \
  do {                                                          \
    WSLOT(P0, 0, ROFF); WSLOT(P1, 1, ROFF); WSLOT(P2, 2, ROFF); \
    WSLOT(P3, 3, ROFF); WSLOT(P4, 4, ROFF); WSLOT(P5, 5, ROFF); \
    WSLOT(P6, 6, ROFF);                                         \
  } while (0)

#define FMA4(WL, P, ACC)                \
  do {                                  \
    ACC.x = fmaf((WL), P.x, ACC.x);     \
    ACC.y = fmaf((WL), P.y, ACC.y);     \
    ACC.z = fmaf((WL), P.z, ACC.z);     \
  } while (0);                          \
  ACC.w = fmaf((WL), P.w, ACC.w)

// MFMA logits: wave w covers tile rows 16w..16w+15 (row clamped to 50; out-
// of-range items masked by nvalid). A-frag from swizzled f32 tile + f2bf;
// B-frag rematerialized from w1t. s-loop unroll(1): spill discipline
// (round-11 proven). C/D: j = lane&15, item = 16w + 4*(lane>>4) + reg.
template <int MODE>  // 0: L-rows; 1: stage2 ([u_long] + S rows)
__device__ __forceinline__ void mfma_logits(
    const float* eb, const unsigned short* w1t,
    int w, int lane, float upart_j, float w2j, float b2v,
    const int* rowm, int nvalid, float* w_sh, float& pacc) {
  const int jj = lane & 15, ko = lane >> 4;
  const int x = lane & 7;              // = row & 7 for valid rows
  const int q0 = (2 * ko) ^ x, q1 = q0 ^ 1;
  const int row = 16 * w + jj;
  const int rowc = (row <= 50) ? row : 50;  // clamp: in-bounds garbage, masked
  const float4* rp = reinterpret_cast<const float4*>(&eb[rowc * 128]);
  const unsigned short* wp = &w1t[jj * 136 + 8 * ko];
  f32x4 acc = {0.f, 0.f, 0.f, 0.f};
#pragma unroll 1  // spill discipline: do NOT hoist all 8 float4 loads
  for (int s = 0; s < 4; ++s) {
    float4 fa = rp[q0 + 8 * s];        // logical quad 2ko+8s
    float4 fb = rp[q1 + 8 * s];        // logical quad 2ko+8s+1
    short8 bfrag = *reinterpret_cast<const short8*>(wp + 32 * s);
    short8 afrag;
    afrag[0] = (short)f2bf(fa.x); afrag[1] = (short)f2bf(fa.y);
    afrag[2] = (short)f2bf(fa.z); afrag[3] = (short)f2bf(fa.w);
    afrag[4] = (short)f2bf(fb.x); afrag[5] = (short)f2bf(fb.y);
    afrag[6] = (short)f2bf(fb.z); afrag[7] = (short)f2bf(fb.w);
    acc = __builtin_amdgcn_mfma_f32_16x16x32_bf16(afrag, bfrag, acc, 0, 0, 0);
  }
  float v0 = fmaxf(upart_j + acc[0], 0.f) * w2j;
  float v1 = fmaxf(upart_j + acc[1], 0.f) * w2j;
  float v2 = fmaxf(upart_j + acc[2], 0.f) * w2j;
  float v3 = fmaxf(upart_j + acc[3], 0.f) * w2j;
#pragma unroll
  for (int m = 1; m <= 8; m <<= 1) {   // reduce over j = lane bits 0..3
    v0 += __shfl_xor(v0, m, 64);
    v1 += __shfl_xor(v1, m, 64);
    v2 += __shfl_xor(v2, m, 64);
    v3 += __shfl_xor(v3, m, 64);
  }
  if ((lane & 15) == 0) {
    const int it0 = 16 * w + 4 * (lane >> 4);
    float p0, p1, p2, p3;
    if (MODE == 0) {
      p0 = (it0 + 0 < nvalid && rowm[it0 + 0] >= 0) ? expf(v0 + b2v) : 0.f;
      p1 = (it0 + 1 < nvalid && rowm[it0 + 1] >= 0) ? expf(v1 + b2v) : 0.f;
      p2 = (it0 + 2 < nvalid && rowm[it0 + 2] >= 0) ? expf(v2 + b2v) : 0.f;
      p3 = (it0 + 3 < nvalid && rowm[it0 + 3] >= 0) ? expf(v3 + b2v) : 0.f;
    } else {  // item 0 = u_long (always valid); item i>=1 masked by rowm[i-1]
      p0 = (it0 == 0) ? expf(v0 + b2v)
                      : ((it0 < nvalid && rowm[it0 - 1] >= 0) ? expf(v0 + b2v) : 0.f);
      p1 = (it0 + 1 < nvalid && rowm[it0 + 0] >= 0) ? expf(v1 + b2v) : 0.f;
      p2 = (it0 + 2 < nvalid && rowm[it0 + 1] >= 0) ? expf(v2 + b2v) : 0.f;
      p3 = (it0 + 3 < nvalid && rowm[it0 + 2] >= 0) ? expf(v3 + b2v) : 0.f;
    }
    float4 pv;
    pv.x = p0; pv.y = p1; pv.z = p2; pv.w = p3;
    reinterpret_cast<float4*>(w_sh)[it0 >> 2] = pv;
    pacc += p0 + p1 + p2 + p3;
  }
}

__global__ void __launch_bounds__(256, 5) din_kernel(
    const float* __restrict__ user_table, const float* __restrict__ item_table,
    const float* __restrict__ W1, const float* __restrict__ b1,
    const float* __restrict__ W2, const float* __restrict__ b2,
    const int* __restrict__ user_inputs, const int* __restrict__ L_inputs,
    const int* __restrict__ S_inputs, const int* __restrict__ item_inputs,
    float* __restrict__ out) {
  __shared__ __align__(16) float ebuf[TROWS * 128];          // 26,112B f32 tile
  __shared__ __align__(16) unsigned short w1t_sh[16 * 136];  // 4,352B W1[128:256] bf16 [j][k]
  __shared__ __align__(16) float w_sh[64];
  __shared__ int rows1[LLEN];
  __shared__ int rowsS[SLEN];
  __shared__ float upart_sh[16];
  __shared__ float red_sh[4];
  // total ~31.8 KB <= 32,768 -> 5 blocks/CU

  const int b = blockIdx.x;
  const int tid = threadIdx.x;
  const int lane = tid & 63;
  const int w = __builtin_amdgcn_readfirstlane(tid >> 6);
  const int col4 = tid & 31;  // logical float4 column (d = 4*col4..+3)
  const int grp = tid >> 5;   // row group 0..7 (== l&7 in all accum loops)
  const float4* it4 = reinterpret_cast<const float4*>(item_table);
  float* scr = &ebuf[0];      // 512-float reduce scratch = tile rows 0..3 (dead windows)

  // ---- prolog: indices + item embedding ----
  const int urow = user_inputs[b];
  const float item_f =
      (tid < D) ? item_table[(size_t)item_inputs[b] * D + tid] : 0.f;
  if (tid < LLEN) rows1[tid] = L_inputs[(size_t)b * LLEN + tid];
  if (tid < SLEN) rowsS[tid] = S_inputs[(size_t)b * SLEN + tid];
  __syncthreads();

  // gather chunk 0 into regs: latency hides under u-part MLP + W1T build
  float4 P0, P1, P2, P3, P4, P5, P6;
  GATHER7(rows1, 0);

  // u_part[j] = b1[j] + u @ W1[0:128,:]  (f32 exact; direct global reads + shfl)
  {
    const int j = tid & 15, g = tid >> 4;
    const float* up = &user_table[(size_t)urow * D + 8 * g];
    const float* wp = &W1[(size_t)(8 * g) * 16 + j];
    float p = 0.f;
#pragma unroll
    for (int t = 0; t < 8; ++t) p = fmaf(up[t], wp[t * 16], p);
    p += __shfl_xor(p, 16, 64);
    p += __shfl_xor(p, 32, 64);          // lanes 0..15 hold wave partial for j
    if (lane < 16) w_sh[w * 16 + lane] = p;
  }
  // W1T build: w1t[j][k] = bf16(W1[128+k][j])
#pragma unroll
  for (int i = 0; i < 8; ++i) {
    int idx = tid + i * 256;             // 0..2047
    int j = idx & 15, k = idx >> 4;
    w1t_sh[j * 136 + k] = f2bf(W1[(size_t)(128 + k) * 16 + j]);
  }
  __syncthreads();  // w_sh partials + W1T visible
  if (tid < 16)
    upart_sh[tid] = b1[tid] + w_sh[tid] + w_sh[16 + tid] + w_sh[32 + tid] +
                    w_sh[48 + tid];
  WRITE7(0);        // chunk 0 -> tile (ebuf untouched by prolog)
  __syncthreads();  // bar A: upart + tile c0 visible

  const float b2v = b2[0];
  const float upart_j = upart_sh[lane & 15];
  const float w2j = W2[lane & 15];

  float pacc = 0.f;
  float4 uacc = make_float4(0.f, 0.f, 0.f, 0.f);

  // ============ stage 1: 4 chunks x 50 rows ============
  // Per chunk: [issue gathers c+1 | MFMA c] -> bar -> accum c -> bar ->
  //            write c+1 -> bar. Gather latency hides under MFMA + accum.
#pragma unroll 1
  for (int c = 0; c < 4; ++c) {
    if (c < 3) GATHER7(rows1, (c + 1) * CH);
    else       GATHER7(rowsS, 0);   // S rows ride the last chunk's window
    mfma_logits<0>(ebuf, w1t_sh, w, lane, upart_j, w2j, b2v,
                   rows1 + c * CH, CH, w_sh, pacc);
    __syncthreads();  // bar B: publish w_sh
#pragma unroll
    for (int i = 0; i < 6; ++i) {
      int l = grp + 8 * i;  // rows 0..47 (l&7 == grp -> constant phys col)
      float wl = w_sh[l];
      const float4 e = reinterpret_cast<const float4*>(&ebuf[l * 128])[col4 ^ grp];
      FMA4(wl, e, uacc);
    }
    if (grp < 2) {  // rows 48..49
      int l = 48 + grp;
      float wl = w_sh[l];
      const float4 e = reinterpret_cast<const float4*>(&ebuf[l * 128])[col4 ^ grp];
      FMA4(wl, e, uacc);
    }
    __syncthreads();  // bar C: accum done -> tile writable
    if (c < 3) {
      WRITE7(0);
      __syncthreads();  // bar A: tile c+1 visible
    }
    // c==3: P holds S rows; written after the u_long reduce below
  }

  // ---- u_long: block_sum (barriers cover tile-free) + reduce via scr ----
  const float invS1 = 1.f / block_sum(pacc, red_sh);
  uacc.x += __shfl_xor(uacc.x, 32, 64);
  uacc.y += __shfl_xor(uacc.y, 32, 64);
  uacc.z += __shfl_xor(uacc.z, 32, 64);
  uacc.w += __shfl_xor(uacc.w, 32, 64);
  if (lane < 32) reinterpret_cast<float4*>(scr)[(w << 5) + lane] = uacc;
  __syncthreads();
  float ulv = 0.f;
  if (tid < D)
    ulv = (scr[tid] + scr[128 + tid] + scr[256 + tid] + scr[384 + tid]) * invS1;
  __syncthreads();  // scr reads done -> rows 0..3 reusable
  if (tid < D) ebuf[tid] = ulv;  // tile row 0 = u_long (swizzle identity at row 0)
  WRITE7(1);                     // S rows -> tile rows 1..50
  __syncthreads();               // row 0 + S rows visible

  // ============ stage 2: [u_long] + 50 S rows (tile rows 0..50) ============
  float pacc2 = 0.f;
  mfma_logits<1>(ebuf, w1t_sh, w, lane, upart_j, w2j, b2v,
                 rowsS, 51, w_sh, pacc2);
  const float invS2 = 1.f / block_sum(pacc2, red_sh);  // barriers publish w_sh

  float4 uacc2 = make_float4(0.f, 0.f, 0.f, 0.f);
#pragma unroll
  for (int i = 0; i < 6; ++i) {
    int l = grp + 8 * i;  // rows 0..47
    float wl = w_sh[l];
    const float4 e = reinterpret_cast<const float4*>(&ebuf[l * 128])[col4 ^ grp];
    FMA4(wl, e, uacc2);
  }
  if (grp < 3) {  // rows 48..50 (l&7 == grp still holds)
    int l = 48 + grp;
    float wl = w_sh[l];
    const float4 e = reinterpret_cast<const float4*>(&ebuf[l * 128])[col4 ^ grp];
    FMA4(wl, e, uacc2);
  }

  uacc2.x += __shfl_xor(uacc2.x, 32, 64);
  uacc2.y += __shfl_xor(uacc2.y, 32, 64);
  uacc2.z += __shfl_xor(uacc2.z, 32, 64);
  uacc2.w += __shfl_xor(uacc2.w, 32, 64);
  __syncthreads();  // stage-2 accum reads of rows 0..3 done before scr overwrite
  if (lane < 32) reinterpret_cast<float4*>(scr)[(w << 5) + lane] = uacc2;
  __syncthreads();

  // ---- score = dot(user_hybrid, item_emb) ----
  float sv = 0.f;
  if (tid < D) {
    float s = scr[tid] + scr[128 + tid] + scr[256 + tid] + scr[384 + tid];
    sv = s * invS2 * item_f;
  }
  float tot = block_sum(sv, red_sh);
  if (tid == 0) out[b] = tot;
}

extern "C" void kernel_launch(void* const* d_in, const int* in_sizes, int n_in,
                              void* d_out, int out_size, void* d_ws, size_t ws_size,
                              hipStream_t stream) {
  const float* user_table = (const float*)d_in[0];
  const float* item_table = (const float*)d_in[1];
  const float* W1 = (const float*)d_in[2];
  const float* b1 = (const float*)d_in[3];
  const float* W2 = (const float*)d_in[4];
  const float* b2 = (const float*)d_in[5];
  const int* user_inputs = (const int*)d_in[6];
  const int* L_inputs = (const int*)d_in[7];
  const int* S_inputs = (const int*)d_in[8];
  const int* item_inputs = (const int*)d_in[9];
  float* out = (float*)d_out;

  const int B = in_sizes[6];  // 4096
  din_kernel<<<B, 256, 0, stream>>>(user_table, item_table, W1, b1, W2, b2,
                                    user_inputs, L_inputs, S_inputs, item_inputs,
                                    out);
}

// Round 14
// 250.191 us; speedup vs baseline: 1.3325x; 1.3325x over previous
//
#include <hip/hip_runtime.h>
#include <math.h>
#include <stdint.h>

#define D 128
#define LLEN 200
#define SLEN 50
// ebuf: 64 rows x 128 f32 (512B rows). Stage 1: wave w owns strip rows
// 16w..16w+15 and processes its own 50 L-rows in 4 sub-chunks (16,16,16,2)
// with NO block barriers (wave-local vmcnt/lgkmcnt only). Stage 2: rows
// 0..50 cooperative (r12 structure). XOR swizzle: phys col4 = logical ^
// (row&7) at stage-source and at read (involution, rule 21).

typedef __attribute__((ext_vector_type(8))) short short8;
typedef __attribute__((ext_vector_type(4))) float f32x4;
typedef __attribute__((address_space(3))) unsigned int lds_uint;
typedef __attribute__((address_space(1))) unsigned int gbl_uint;

// f32 -> bf16 round-to-nearest-even
__device__ __forceinline__ unsigned short f2bf(float f) {
  unsigned int u = __float_as_uint(f);
  return (unsigned short)((u + 0x7FFFu + ((u >> 16) & 1u)) >> 16);
}

__device__ __forceinline__ float wave_red_sum(float v) {
#pragma unroll
  for (int m = 32; m >= 1; m >>= 1) v += __shfl_xor(v, m, 64);
  return v;
}
// 256-thread block sum; ALL threads must call.
__device__ __forceinline__ float block_sum(float v, float* red) {
  v = wave_red_sum(v);
  if ((threadIdx.x & 63) == 0) red[threadIdx.x >> 6] = v;
  __syncthreads();
  v = red[0] + red[1] + red[2] + red[3];
  __syncthreads();
  return v;
}

// Wave-private stage: slot t = lane + IT*64 -> strip row R0 + (t>>5),
// 16B col (t&31). LDS dest = wave-uniform base + lane*16 (linear; the
// swizzle is pre-applied to the GLOBAL source column).
#define STAGEW(IT, LBASE)                                                   \
  do {                                                                      \
    const int t_ = lane + (IT) * 64;                                        \
    const int rl_ = t_ >> 5;                                                \
    int gid_ = rows1[(LBASE) + rl_];                                        \
    if (gid_ < 0) gid_ = 0;                                                 \
    const float4* src_ =                                                    \
        &it4[(size_t)gid_ * 32 + ((t_ & 31) ^ ((R0 + rl_) & 7))];           \
    __builtin_amdgcn_global_load_lds(                                       \
        (const gbl_uint*)(uintptr_t)src_,                                   \
        (lds_uint*)(uintptr_t)(&ebuf[R0 * 128 + (IT) * 256]), 16, 0, 0);    \
  } while (0)

#define STAGEW8(LBASE)                                        \
  do {                                                        \
    STAGEW(0, LBASE); STAGEW(1, LBASE); STAGEW(2, LBASE);     \
    STAGEW(3, LBASE); STAGEW(4, LBASE); STAGEW(5, LBASE);     \
    STAGEW(6, LBASE); STAGEW(7, LBASE);                       \
  } while (0)

// Cooperative S-row stage (256 threads) -> tile rows 1..50 (r12 pattern).
#define STAGE_S(IT)                                                          \
  do {                                                                       \
    const int s_ = tid + (IT) * 256;                                         \
    const int rr_ = (s_ >> 5) + 1;                                           \
    int gid_ = rowsS[s_ >> 5];                                               \
    if (gid_ < 0) gid_ = 0;                                                  \
    const float4* src_ = &it4[(size_t)gid_ * 32 + ((s_ & 31) ^ (rr_ & 7))];  \
    __builtin_amdgcn_global_load_lds(                                        \
        (const gbl_uint*)(uintptr_t)src_,                                    \
        (lds_uint*)(uintptr_t)(&ebuf[((tid & 192) + (IT) * 256) * 4 + 128]), \
        16, 0, 0);                                                           \
  } while (0)

#define FMA4(WL, P, ACC)                \
  do {                                  \
    ACC.x = fmaf((WL), P.x, ACC.x);     \
    ACC.y = fmaf((WL), P.y, ACC.y);     \
    ACC.z = fmaf((WL), P.z, ACC.z);     \
  } while (0);                          \
  ACC.w = fmaf((WL), P.w, ACC.w)

// MFMA logits: wave w reads strip rows 16w..16w+15 (MODE 0: no clamp —
// wave 3's strip rows 48..63 are all valid LDS; MODE 1: clamp 50 for the
// 51-row stage-2 tile). Items: it0 = 16w + 4*(lane>>4); caller adjusts
// rowm/nvalid so masks index the right row array. w_sh[16w..16w+16) is
// WAVE-PRIVATE (written by own lanes, read only by own wave -> no barrier).
// s-loop unroll(1): spill discipline (round-11). C/D: j = lane&15,
// item = 16w + 4*(lane>>4) + reg [m89-verified].
template <int MODE>  // 0: stage-1 wave-private; 1: stage2 ([u_long] + S)
__device__ __forceinline__ void mfma_logits(
    const float* eb, const unsigned short* w1t,
    int w, int lane, float upart_j, float w2j, float b2v,
    const int* rowm, int nvalid, float* w_sh, float& pacc) {
  const int jj = lane & 15, ko = lane >> 4;
  const int row = 16 * w + jj;
  const int rowc = (MODE == 1 && row > 50) ? 50 : row;
  const int x = rowc & 7;
  const int q0 = (2 * ko) ^ x, q1 = q0 ^ 1;
  const float4* rp = reinterpret_cast<const float4*>(&eb[rowc * 128]);
  const unsigned short* wp = &w1t[jj * 136 + 8 * ko];
  f32x4 acc = {0.f, 0.f, 0.f, 0.f};
#pragma unroll 1  // spill discipline: do NOT hoist all 8 float4 loads
  for (int s = 0; s < 4; ++s) {
    float4 fa = rp[q0 + 8 * s];        // logical quad 2ko+8s
    float4 fb = rp[q1 + 8 * s];        // logical quad 2ko+8s+1
    short8 bfrag = *reinterpret_cast<const short8*>(wp + 32 * s);
    short8 afrag;
    afrag[0] = (short)f2bf(fa.x); afrag[1] = (short)f2bf(fa.y);
    afrag[2] = (short)f2bf(fa.z); afrag[3] = (short)f2bf(fa.w);
    afrag[4] = (short)f2bf(fb.x); afrag[5] = (short)f2bf(fb.y);
    afrag[6] = (short)f2bf(fb.z); afrag[7] = (short)f2bf(fb.w);
    acc = __builtin_amdgcn_mfma_f32_16x16x32_bf16(afrag, bfrag, acc, 0, 0, 0);
  }
  float v0 = fmaxf(upart_j + acc[0], 0.f) * w2j;
  float v1 = fmaxf(upart_j + acc[1], 0.f) * w2j;
  float v2 = fmaxf(upart_j + acc[2], 0.f) * w2j;
  float v3 = fmaxf(upart_j + acc[3], 0.f) * w2j;
#pragma unroll
  for (int m = 1; m <= 8; m <<= 1) {   // reduce over j = lane bits 0..3
    v0 += __shfl_xor(v0, m, 64);
    v1 += __shfl_xor(v1, m, 64);
    v2 += __shfl_xor(v2, m, 64);
    v3 += __shfl_xor(v3, m, 64);
  }
  if ((lane & 15) == 0) {
    const int it0 = 16 * w + 4 * (lane >> 4);
    float p0, p1, p2, p3;
    if (MODE == 0) {
      p0 = (it0 + 0 < nvalid && rowm[it0 + 0] >= 0) ? expf(v0 + b2v) : 0.f;
      p1 = (it0 + 1 < nvalid && rowm[it0 + 1] >= 0) ? expf(v1 + b2v) : 0.f;
      p2 = (it0 + 2 < nvalid && rowm[it0 + 2] >= 0) ? expf(v2 + b2v) : 0.f;
      p3 = (it0 + 3 < nvalid && rowm[it0 + 3] >= 0) ? expf(v3 + b2v) : 0.f;
    } else {  // item 0 = u_long (always valid); item i>=1 masked by rowm[i-1]
      p0 = (it0 == 0) ? expf(v0 + b2v)
                      : ((it0 < nvalid && rowm[it0 - 1] >= 0) ? expf(v0 + b2v) : 0.f);
      p1 = (it0 + 1 < nvalid && rowm[it0 + 0] >= 0) ? expf(v1 + b2v) : 0.f;
      p2 = (it0 + 2 < nvalid && rowm[it0 + 1] >= 0) ? expf(v2 + b2v) : 0.f;
      p3 = (it0 + 3 < nvalid && rowm[it0 + 2] >= 0) ? expf(v3 + b2v) : 0.f;
    }
    float4 pv;
    pv.x = p0; pv.y = p1; pv.z = p2; pv.w = p3;
    reinterpret_cast<float4*>(w_sh)[it0 >> 2] = pv;
    pacc += p0 + p1 + p2 + p3;
  }
}

__global__ void __launch_bounds__(256, 4) din_kernel(
    const float* __restrict__ user_table, const float* __restrict__ item_table,
    const float* __restrict__ W1, const float* __restrict__ b1,
    const float* __restrict__ W2, const float* __restrict__ b2,
    const int* __restrict__ user_inputs, const int* __restrict__ L_inputs,
    const int* __restrict__ S_inputs, const int* __restrict__ item_inputs,
    float* __restrict__ out) {
  __shared__ __align__(16) float ebuf[64 * 128];             // 32 KB: 4 wave strips
  __shared__ __align__(16) unsigned short w1t_sh[16 * 136];  // W1[128:256] bf16 [j][k]
  __shared__ __align__(16) float w_sh[64];                   // wave-private slices
  __shared__ int rows1[LLEN];
  __shared__ int rowsS[SLEN];
  __shared__ float upart_sh[16];
  __shared__ float red_sh[4];
  // total ~38.4 KB -> 4 blocks/CU (16 independent wave pipelines)

  const int b = blockIdx.x;
  const int tid = threadIdx.x;
  const int lane = tid & 63;
  const int w = __builtin_amdgcn_readfirstlane(tid >> 6);
  const int R0 = 16 * w;      // own strip base row
  const int par = lane >> 5;  // row parity within strip accum
  const int c32 = lane & 31;  // logical float4 column
  const float4* it4 = reinterpret_cast<const float4*>(item_table);
  float* scr = &ebuf[0];      // 512-float reduce scratch (rows 0..3, dead windows)

  // ---- prolog: indices + item embedding ----
  const int urow = user_inputs[b];
  const float item_f =
      (tid < D) ? item_table[(size_t)item_inputs[b] * D + tid] : 0.f;
  if (tid < LLEN) rows1[tid] = L_inputs[(size_t)b * LLEN + tid];
  if (tid < SLEN) rowsS[tid] = S_inputs[(size_t)b * SLEN + tid];
  __syncthreads();

  // stage own sub-chunk 0 (L rows 50w..50w+15): hides under prolog MLP
  STAGEW8(50 * w);

  // u_part[j] = b1[j] + u @ W1[0:128,:]  (f32 exact; direct global + shfl)
  {
    const int j = tid & 15, g = tid >> 4;
    const float* up = &user_table[(size_t)urow * D + 8 * g];
    const float* wp = &W1[(size_t)(8 * g) * 16 + j];
    float p = 0.f;
#pragma unroll
    for (int t = 0; t < 8; ++t) p = fmaf(up[t], wp[t * 16], p);
    p += __shfl_xor(p, 16, 64);
    p += __shfl_xor(p, 32, 64);          // lanes 0..15 hold wave partial for j
    if (lane < 16) w_sh[w * 16 + lane] = p;
  }
  // W1T build: w1t[j][k] = bf16(W1[128+k][j])
#pragma unroll
  for (int i = 0; i < 8; ++i) {
    int idx = tid + i * 256;             // 0..2047
    int j = idx & 15, k = idx >> 4;
    w1t_sh[j * 136 + k] = f2bf(W1[(size_t)(128 + k) * 16 + j]);
  }
  __syncthreads();  // w_sh partials + W1T visible
  if (tid < 16)
    upart_sh[tid] = b1[tid] + w_sh[tid] + w_sh[16 + tid] + w_sh[32 + tid] +
                    w_sh[48 + tid];
  __syncthreads();

  const float b2v = b2[0];
  const float upart_j = upart_sh[lane & 15];
  const float w2j = W2[lane & 15];

  float pacc = 0.f;
  float4 uacc = make_float4(0.f, 0.f, 0.f, 0.f);

  // ============ stage 1: wave-private, ZERO block barriers ============
  // Per sub-chunk: vmcnt(0) [wave-local] -> MFMA (own strip, own w_sh
  // slice) -> accum own rows -> lgkmcnt(0) -> stage next sub-chunk.
#pragma unroll 1
  for (int s = 0; s < 4; ++s) {
    const int cs = (s < 3) ? 16 : 2;
    asm volatile("s_waitcnt vmcnt(0)" ::: "memory");  // own stage landed
    __builtin_amdgcn_sched_barrier(0);
    // rowm offset so rowm[it0+k] = rows1[50w+16s + local]; nvalid = R0+cs
    mfma_logits<0>(ebuf, w1t_sh, w, lane, upart_j, w2j, b2v,
                   rows1 + 34 * w + 16 * s, R0 + cs, w_sh, pacc);
    // wave-local accum: rows R0+par+2i, 32 lanes x full row (stride-1 quads)
#pragma unroll
    for (int i = 0; i < 8; ++i) {
      if (par + 2 * i < cs) {
        const int l = R0 + par + 2 * i;
        float wl = w_sh[l];
        const float4 e =
            reinterpret_cast<const float4*>(&ebuf[l * 128])[c32 ^ (l & 7)];
        FMA4(wl, e, uacc);
      }
    }
    if (s < 3) {
      asm volatile("s_waitcnt lgkmcnt(0)" ::: "memory");  // strip reads done
      __builtin_amdgcn_sched_barrier(0);                  // pin stage after
      const int nb = 50 * w + 16 * (s + 1);
      if (s < 2) STAGEW8(nb);
      else       STAGEW(0, nb);  // final sub-chunk: 2 rows = 64 slots
    }
  }

  // ---- u_long: block_sum (first cross-wave sync) + reduce via scr ----
  const float invS1 = 1.f / block_sum(pacc, red_sh);
  uacc.x += __shfl_xor(uacc.x, 32, 64);
  uacc.y += __shfl_xor(uacc.y, 32, 64);
  uacc.z += __shfl_xor(uacc.z, 32, 64);
  uacc.w += __shfl_xor(uacc.w, 32, 64);
  if (lane < 32) reinterpret_cast<float4*>(scr)[(w << 5) + lane] = uacc;
  __syncthreads();
  float ulv = 0.f;
  if (tid < D)
    ulv = (scr[tid] + scr[128 + tid] + scr[256 + tid] + scr[384 + tid]) * invS1;
  __syncthreads();  // scr reads done -> rows 0..3 reusable
  if (tid < D) ebuf[tid] = ulv;  // tile row 0 = u_long (swizzle identity row 0)
  // S rows -> tile rows 1..50 (cooperative)
  STAGE_S(0); STAGE_S(1); STAGE_S(2); STAGE_S(3); STAGE_S(4); STAGE_S(5);
  if (tid < 64) STAGE_S(6);
  __syncthreads();  // row 0 + S rows visible (vmcnt drained at barrier)

  // ============ stage 2: [u_long] + 50 S rows (tile rows 0..50) ============
  float pacc2 = 0.f;
  mfma_logits<1>(ebuf, w1t_sh, w, lane, upart_j, w2j, b2v,
                 rowsS, 51, w_sh, pacc2);
  float4 uacc2 = make_float4(0.f, 0.f, 0.f, 0.f);
#pragma unroll
  for (int i = 0; i < 8; ++i) {
    const int l = R0 + par + 2 * i;
    if (l < 51) {  // wave-private w_sh slice + own rows -> no barrier needed
      float wl = w_sh[l];
      const float4 e =
          reinterpret_cast<const float4*>(&ebuf[l * 128])[c32 ^ (l & 7)];
      FMA4(wl, e, uacc2);
    }
  }
  const float invS2 = 1.f / block_sum(pacc2, red_sh);  // cross-wave sync
  uacc2.x += __shfl_xor(uacc2.x, 32, 64);
  uacc2.y += __shfl_xor(uacc2.y, 32, 64);
  uacc2.z += __shfl_xor(uacc2.z, 32, 64);
  uacc2.w += __shfl_xor(uacc2.w, 32, 64);
  if (lane < 32) reinterpret_cast<float4*>(scr)[(w << 5) + lane] = uacc2;
  __syncthreads();

  // ---- score = dot(user_hybrid, item_emb) ----
  float sv = 0.f;
  if (tid < D) {
    float s = scr[tid] + scr[128 + tid] + scr[256 + tid] + scr[384 + tid];
    sv = s * invS2 * item_f;
  }
  float tot = block_sum(sv, red_sh);
  if (tid == 0) out[b] = tot;
}

extern "C" void kernel_launch(void* const* d_in, const int* in_sizes, int n_in,
                              void* d_out, int out_size, void* d_ws, size_t ws_size,
                              hipStream_t stream) {
  const float* user_table = (const float*)d_in[0];
  const float* item_table = (const float*)d_in[1];
  const float* W1 = (const float*)d_in[2];
  const float* b1 = (const float*)d_in[3];
  const float* W2 = (const float*)d_in[4];
  const float* b2 = (const float*)d_in[5];
  const int* user_inputs = (const int*)d_in[6];
  const int* L_inputs = (const int*)d_in[7];
  const int* S_inputs = (const int*)d_in[8];
  const int* item_inputs = (const int*)d_in[9];
  float* out = (float*)d_out;

  const int B = in_sizes[6];  // 4096
  din_kernel<<<B, 256, 0, stream>>>(user_table, item_table, W1, b1, W2, b2,
                                    user_inputs, L_inputs, S_inputs, item_inputs,
                                    out);
}

// Round 15
// 248.482 us; speedup vs baseline: 1.3417x; 1.0069x over previous
//
#include <hip/hip_runtime.h>
#include <math.h>
#include <stdint.h>

#define D 128
#define LLEN 200
#define SLEN 50
#define CH 50     // stage-1 chunk rows; 4*50 = 200 exactly -> no tail path
#define TROWS 51  // tile rows (stage 2 needs [u_long]+50)
// f32 tile: 51 rows x 128 floats (512B rows, linear for global_load_lds).
// XOR swizzle: phys col4 = logical col4 ^ (row&7) at stage-source and read.
// Accum is WAVE-PRIVATE (r14-proven): wave w consumes the w_sh slice and
// logit rows it computed itself -> no publish barrier (2 bars/chunk, not 3).

typedef __attribute__((ext_vector_type(8))) short short8;
typedef __attribute__((ext_vector_type(4))) float f32x4;
typedef __attribute__((address_space(3))) unsigned int lds_uint;
typedef __attribute__((address_space(1))) unsigned int gbl_uint;

// f32 -> bf16 round-to-nearest-even
__device__ __forceinline__ unsigned short f2bf(float f) {
  unsigned int u = __float_as_uint(f);
  return (unsigned short)((u + 0x7FFFu + ((u >> 16) & 1u)) >> 16);
}

__device__ __forceinline__ float wave_red_sum(float v) {
#pragma unroll
  for (int m = 32; m >= 1; m >>= 1) v += __shfl_xor(v, m, 64);
  return v;
}
// 256-thread block sum; ALL threads must call.
__device__ __forceinline__ float block_sum(float v, float* red) {
  v = wave_red_sum(v);
  if ((threadIdx.x & 63) == 0) red[threadIdx.x >> 6] = v;
  __syncthreads();
  v = red[0] + red[1] + red[2] + red[3];
  __syncthreads();
  return v;
}

// Stage one 16B slot HBM->LDS via global_load_lds (no VGPR round-trip).
// slot s = tid + IT*256; tile row = (s>>5)+ROFF; source col pre-swizzled.
#define STAGE(ROWARR, RBASE, IT, ROFF)                                        \
  do {                                                                        \
    const int s_ = tid + (IT) * 256;                                          \
    const int rr_ = (s_ >> 5) + (ROFF);                                       \
    int gid_ = ROWARR[(RBASE) + (s_ >> 5)];                                   \
    if (gid_ < 0) gid_ = 0;                                                   \
    const float4* src_ = &it4[(size_t)gid_ * 32 + ((s_ & 31) ^ (rr_ & 7))];   \
    __builtin_amdgcn_global_load_lds(                                         \
        (const gbl_uint*)(uintptr_t)src_,                                     \
        (lds_uint*)(uintptr_t)(&ebuf[((tid & 192) + (IT) * 256) * 4 +         \
                                     (ROFF) * 128]),                          \
        16, 0, 0);                                                            \
  } while (0)

// 50 rows = 1600 slots: 6 full iters + 64-slot remainder (wave 0 only)
#define STAGE_CHUNK(RB)                                                \
  do {                                                                 \
    STAGE(rows1, RB, 0, 0); STAGE(rows1, RB, 1, 0);                    \
    STAGE(rows1, RB, 2, 0); STAGE(rows1, RB, 3, 0);                    \
    STAGE(rows1, RB, 4, 0); STAGE(rows1, RB, 5, 0);                    \
    if (tid < 64) STAGE(rows1, RB, 6, 0);                              \
  } while (0)

#define FMA4(WL, P, ACC)                \
  do {                                  \
    ACC.x = fmaf((WL), P.x, ACC.x);     \
    ACC.y = fmaf((WL), P.y, ACC.y);     \
    ACC.z = fmaf((WL), P.z, ACC.z);     \
  } while (0);                          \
  ACC.w = fmaf((WL), P.w, ACC.w)

// Wave-private accum (r14-proven pattern): wave w owns rows R0+par+2i
// (i = 0..7); each par-group's 32 lanes read one full row as 32 swizzled
// quads. w_sh slice was written by this wave's own mfma -> NO barrier.
#define ACCUM_OWN(NROWS, ACC)                                             \
  _Pragma("unroll")                                                       \
  for (int i_ = 0; i_ < 8; ++i_) {                                        \
    const int l_ = R0 + par + 2 * i_;                                     \
    if (l_ < (NROWS)) {                                                   \
      float wl_ = w_sh[l_];                                               \
      const float4 e_ =                                                   \
          reinterpret_cast<const float4*>(&ebuf[l_ * 128])[c32 ^ (l_ & 7)]; \
      FMA4(wl_, e_, ACC);                                                 \
    }                                                                     \
  }

// MFMA logits: wave w covers tile rows 16w..16w+15 (row clamped to 50 for
// in-bounds reads of the 51-row tile; out-of-range items masked by nvalid).
// A-frag from swizzled f32 tile + f2bf; B-frag rematerialized from w1t.
// s-loop unroll(1): spill discipline (round-11 proven). C/D: j = lane&15,
// item = 16w + 4*(lane>>4) + reg  [m89-verified layout].
template <int MODE>  // 0: L-rows; 1: stage2 ([u_long] + S rows)
__device__ __forceinline__ void mfma_logits(
    const float* eb, const unsigned short* w1t,
    int w, int lane, float upart_j, float w2j, float b2v,
    const int* rowm, int nvalid, float* w_sh, float& pacc) {
  const int jj = lane & 15, ko = lane >> 4;
  const int row = 16 * w + jj;
  const int rowc = (row <= 50) ? row : 50;  // clamp: in-bounds garbage, masked
  const int x = rowc & 7;
  const int q0 = (2 * ko) ^ x, q1 = q0 ^ 1;
  const float4* rp = reinterpret_cast<const float4*>(&eb[rowc * 128]);
  const unsigned short* wp = &w1t[jj * 136 + 8 * ko];
  f32x4 acc = {0.f, 0.f, 0.f, 0.f};
#pragma unroll 1  // spill discipline: do NOT hoist all 8 float4 loads
  for (int s = 0; s < 4; ++s) {
    float4 fa = rp[q0 + 8 * s];        // logical quad 2ko+8s
    float4 fb = rp[q1 + 8 * s];        // logical quad 2ko+8s+1
    short8 bfrag = *reinterpret_cast<const short8*>(wp + 32 * s);
    short8 afrag;
    afrag[0] = (short)f2bf(fa.x); afrag[1] = (short)f2bf(fa.y);
    afrag[2] = (short)f2bf(fa.z); afrag[3] = (short)f2bf(fa.w);
    afrag[4] = (short)f2bf(fb.x); afrag[5] = (short)f2bf(fb.y);
    afrag[6] = (short)f2bf(fb.z); afrag[7] = (short)f2bf(fb.w);
    acc = __builtin_amdgcn_mfma_f32_16x16x32_bf16(afrag, bfrag, acc, 0, 0, 0);
  }
  float v0 = fmaxf(upart_j + acc[0], 0.f) * w2j;
  float v1 = fmaxf(upart_j + acc[1], 0.f) * w2j;
  float v2 = fmaxf(upart_j + acc[2], 0.f) * w2j;
  float v3 = fmaxf(upart_j + acc[3], 0.f) * w2j;
#pragma unroll
  for (int m = 1; m <= 8; m <<= 1) {   // reduce over j = lane bits 0..3
    v0 += __shfl_xor(v0, m, 64);
    v1 += __shfl_xor(v1, m, 64);
    v2 += __shfl_xor(v2, m, 64);
    v3 += __shfl_xor(v3, m, 64);
  }
  if ((lane & 15) == 0) {
    const int it0 = 16 * w + 4 * (lane >> 4);
    float p0, p1, p2, p3;
    if (MODE == 0) {
      p0 = (it0 + 0 < nvalid && rowm[it0 + 0] >= 0) ? expf(v0 + b2v) : 0.f;
      p1 = (it0 + 1 < nvalid && rowm[it0 + 1] >= 0) ? expf(v1 + b2v) : 0.f;
      p2 = (it0 + 2 < nvalid && rowm[it0 + 2] >= 0) ? expf(v2 + b2v) : 0.f;
      p3 = (it0 + 3 < nvalid && rowm[it0 + 3] >= 0) ? expf(v3 + b2v) : 0.f;
    } else {  // item 0 = u_long (always valid); item i>=1 masked by rowm[i-1]
      p0 = (it0 == 0) ? expf(v0 + b2v)
                      : ((it0 < nvalid && rowm[it0 - 1] >= 0) ? expf(v0 + b2v) : 0.f);
      p1 = (it0 + 1 < nvalid && rowm[it0 + 0] >= 0) ? expf(v1 + b2v) : 0.f;
      p2 = (it0 + 2 < nvalid && rowm[it0 + 1] >= 0) ? expf(v2 + b2v) : 0.f;
      p3 = (it0 + 3 < nvalid && rowm[it0 + 2] >= 0) ? expf(v3 + b2v) : 0.f;
    }
    float4 pv;
    pv.x = p0; pv.y = p1; pv.z = p2; pv.w = p3;
    reinterpret_cast<float4*>(w_sh)[it0 >> 2] = pv;
    pacc += p0 + p1 + p2 + p3;
  }
}

__global__ void __launch_bounds__(256, 5) din_kernel(
    const float* __restrict__ user_table, const float* __restrict__ item_table,
    const float* __restrict__ W1, const float* __restrict__ b1,
    const float* __restrict__ W2, const float* __restrict__ b2,
    const int* __restrict__ user_inputs, const int* __restrict__ L_inputs,
    const int* __restrict__ S_inputs, const int* __restrict__ item_inputs,
    float* __restrict__ out) {
  __shared__ __align__(16) float ebuf[TROWS * 128];          // 26,112B f32 tile
  __shared__ __align__(16) unsigned short w1t_sh[16 * 136];  // 4,352B W1[128:256] bf16 [j][k]
  __shared__ __align__(16) float w_sh[64];
  __shared__ int rows1[LLEN];
  __shared__ int rowsS[SLEN];
  __shared__ float upart_sh[16];
  __shared__ float red_sh[4];
  // total ~31.8 KB <= 32,768 -> 5 blocks/CU

  const int b = blockIdx.x;
  const int tid = threadIdx.x;
  const int lane = tid & 63;
  const int w = __builtin_amdgcn_readfirstlane(tid >> 6);
  const int R0 = 16 * w;      // own logit-row slice base
  const int par = lane >> 5;  // row parity within slice
  const int c32 = lane & 31;  // logical float4 column
  const float4* it4 = reinterpret_cast<const float4*>(item_table);
  float* scr = &ebuf[0];      // 512-float reduce scratch = tile rows 0..3 (dead windows)

  // ---- prolog: indices + item embedding ----
  const int urow = user_inputs[b];
  const float item_f =
      (tid < D) ? item_table[(size_t)item_inputs[b] * D + tid] : 0.f;
  if (tid < LLEN) rows1[tid] = L_inputs[(size_t)b * LLEN + tid];
  if (tid < SLEN) rowsS[tid] = S_inputs[(size_t)b * SLEN + tid];
  __syncthreads();

  // stage chunk 0 NOW: latency hides under u-part MLP + W1T build
  STAGE_CHUNK(0);

  // u_part[j] = b1[j] + u @ W1[0:128,:]  (f32 exact; direct global reads + shfl)
  {
    const int j = tid & 15, g = tid >> 4;
    const float* up = &user_table[(size_t)urow * D + 8 * g];
    const float* wp = &W1[(size_t)(8 * g) * 16 + j];
    float p = 0.f;
#pragma unroll
    for (int t = 0; t < 8; ++t) p = fmaf(up[t], wp[t * 16], p);
    p += __shfl_xor(p, 16, 64);
    p += __shfl_xor(p, 32, 64);          // lanes 0..15 hold wave partial for j
    if (lane < 16) w_sh[w * 16 + lane] = p;
  }
  // W1T build: w1t[j][k] = bf16(W1[128+k][j])
#pragma unroll
  for (int i = 0; i < 8; ++i) {
    int idx = tid + i * 256;             // 0..2047
    int j = idx & 15, k = idx >> 4;
    w1t_sh[j * 136 + k] = f2bf(W1[(size_t)(128 + k) * 16 + j]);
  }
  __syncthreads();  // w_sh partials + W1T visible; drains chunk-0 stage
  if (tid < 16)
    upart_sh[tid] = b1[tid] + w_sh[tid] + w_sh[16 + tid] + w_sh[32 + tid] +
                    w_sh[48 + tid];
  __syncthreads();

  const float b2v = b2[0];
  const float upart_j = upart_sh[lane & 15];
  const float w2j = W2[lane & 15];

  float pacc = 0.f;
  float4 uacc = make_float4(0.f, 0.f, 0.f, 0.f);

  // ============ stage 1: 4 chunks x 50 rows, 2 barriers/chunk ============
  // Per chunk: MFMA -> [no bar: w_sh slice + rows are wave-own] -> accum
  //            -> bar (tile reads done) -> STAGE(next) -> bar (drained)
#pragma unroll 1
  for (int c = 0; c < 4; ++c) {
    mfma_logits<0>(ebuf, w1t_sh, w, lane, upart_j, w2j, b2v,
                   rows1 + c * CH, CH, w_sh, pacc);
    ACCUM_OWN(CH, uacc);  // wave-private: no publish barrier needed
    if (c < 3) {
      __syncthreads();          // all tile reads done -> tile writable
      STAGE_CHUNK((c + 1) * CH);
      __syncthreads();          // stage drained (vmcnt(0) at barrier)
    }
  }

  // ---- u_long: block_sum (provides barrier after last accum) + reduce ----
  const float invS1 = 1.f / block_sum(pacc, red_sh);
  uacc.x += __shfl_xor(uacc.x, 32, 64);
  uacc.y += __shfl_xor(uacc.y, 32, 64);
  uacc.z += __shfl_xor(uacc.z, 32, 64);
  uacc.w += __shfl_xor(uacc.w, 32, 64);
  if (lane < 32) reinterpret_cast<float4*>(scr)[(w << 5) + lane] = uacc;
  __syncthreads();
  float ulv = 0.f;
  if (tid < D)
    ulv = (scr[tid] + scr[128 + tid] + scr[256 + tid] + scr[384 + tid]) * invS1;
  __syncthreads();  // scr reads done -> rows 0..3 reusable
  if (tid < D) ebuf[tid] = ulv;  // tile row 0 = u_long (swizzle identity at row 0)
  // S rows -> tile rows 1..50 (slots 0..1599, ROFF=1)
  STAGE(rowsS, 0, 0, 1); STAGE(rowsS, 0, 1, 1); STAGE(rowsS, 0, 2, 1);
  STAGE(rowsS, 0, 3, 1); STAGE(rowsS, 0, 4, 1); STAGE(rowsS, 0, 5, 1);
  if (tid < 64) STAGE(rowsS, 0, 6, 1);
  __syncthreads();  // row 0 + S rows visible (stage drained)

  // ============ stage 2: [u_long] + 50 S rows (tile rows 0..50) ============
  float pacc2 = 0.f;
  mfma_logits<1>(ebuf, w1t_sh, w, lane, upart_j, w2j, b2v,
                 rowsS, 51, w_sh, pacc2);
  float4 uacc2 = make_float4(0.f, 0.f, 0.f, 0.f);
  ACCUM_OWN(51, uacc2);  // wave-private: own w_sh slice, staged rows
  const float invS2 = 1.f / block_sum(pacc2, red_sh);  // cross-wave sync

  uacc2.x += __shfl_xor(uacc2.x, 32, 64);
  uacc2.y += __shfl_xor(uacc2.y, 32, 64);
  uacc2.z += __shfl_xor(uacc2.z, 32, 64);
  uacc2.w += __shfl_xor(uacc2.w, 32, 64);
  if (lane < 32) reinterpret_cast<float4*>(scr)[(w << 5) + lane] = uacc2;
  __syncthreads();

  // ---- score = dot(user_hybrid, item_emb) ----
  float sv = 0.f;
  if (tid < D) {
    float s = scr[tid] + scr[128 + tid] + scr[256 + tid] + scr[384 + tid];
    sv = s * invS2 * item_f;
  }
  float tot = block_sum(sv, red_sh);
  if (tid == 0) out[b] = tot;
}

extern "C" void kernel_launch(void* const* d_in, const int* in_sizes, int n_in,
                              void* d_out, int out_size, void* d_ws, size_t ws_size,
                              hipStream_t stream) {
  const float* user_table = (const float*)d_in[0];
  const float* item_table = (const float*)d_in[1];
  const float* W1 = (const float*)d_in[2];
  const float* b1 = (const float*)d_in[3];
  const float* W2 = (const float*)d_in[4];
  const float* b2 = (const float*)d_in[5];
  const int* user_inputs = (const int*)d_in[6];
  const int* L_inputs = (const int*)d_in[7];
  const int* S_inputs = (const int*)d_in[8];
  const int* item_inputs = (const int*)d_in[9];
  float* out = (float*)d_out;

  const int B = in_sizes[6];  // 4096
  din_kernel<<<B, 256, 0, stream>>>(user_table, item_table, W1, b1, W2, b2,
                                    user_inputs, L_inputs, S_inputs, item_inputs,
                                    out);
}